// Round 6
// baseline (215.550 us; speedup 1.0000x reference)
//
#include <hip/hip_runtime.h>
#include <hip/hip_bf16.h>

// Problem constants
#define B_  2
#define N_  2048
#define D_  1024
#define H_  16
#define DH_ 64
#define BN_ (B_*N_)   // 4096 rows total

typedef __attribute__((ext_vector_type(8))) short short8;    // 8 bf16 (K=16/32 A/B frag)
typedef __attribute__((ext_vector_type(4))) float f32x4;     // 16x16 C/D frag
typedef __attribute__((ext_vector_type(16))) float f32x16;   // 32x32 C/D frag
typedef __attribute__((ext_vector_type(4))) unsigned int uint4v;

typedef __attribute__((address_space(3))) unsigned int lds_u32_t;
typedef const __attribute__((address_space(1))) unsigned int glb_u32_t;

// async global->LDS, 16B per lane; LDS dst = (wave-uniform base) + lane*16
__device__ __forceinline__ void async_load16(const unsigned short* g, unsigned short* l) {
    __builtin_amdgcn_global_load_lds((glb_u32_t*)g, (lds_u32_t*)l, 16, 0, 0);
}

__device__ __forceinline__ unsigned short f2bf(float f) {
    __hip_bfloat16 h = __float2bfloat16(f);
    return *reinterpret_cast<unsigned short*>(&h);
}

// pack bf16(a) low16 | bf16(b) high16; round-half-up + one v_perm_b32
__device__ __forceinline__ unsigned int pkbf(float a, float b) {
    unsigned int ua = __float_as_uint(a) + 0x8000u;
    unsigned int ub = __float_as_uint(b) + 0x8000u;
    return __builtin_amdgcn_perm(ub, ua, 0x07060302);
}

#if __has_builtin(__builtin_amdgcn_exp2f)
#define EXP2(x) __builtin_amdgcn_exp2f(x)
#else
#define EXP2(x) exp2f(x)
#endif

// softmax scale folded into Q projection: 1/sqrt(DH) * log2(e)
#define QSCL 0.1803368801111204f

// ---------------------------------------------------------------------------
// Kernel 1: cast fp32 -> bf16 for x, Wq, Wk, Wv, Wo (one fused launch)
// ---------------------------------------------------------------------------
__global__ __launch_bounds__(256) void cast_kernel(
    const float* __restrict__ x,  const float* __restrict__ wq,
    const float* __restrict__ wk, const float* __restrict__ wv,
    const float* __restrict__ wo,
    unsigned short* __restrict__ xb,  unsigned short* __restrict__ wqb,
    unsigned short* __restrict__ wkb, unsigned short* __restrict__ wvb,
    unsigned short* __restrict__ wob)
{
    const size_t NX = (size_t)BN_ * D_;   // 4194304
    const size_t NW = (size_t)D_ * D_;    // 1048576 (pow2)
    size_t i = ((size_t)blockIdx.x * 256 + threadIdx.x) * 4;
    const float* src; unsigned short* dst; size_t off;
    if (i < NX) { src = x; dst = xb; off = i; }
    else {
        size_t j = (i - NX) >> 20;          // which W
        off = (i - NX) & (NW - 1);
        src = (j == 0) ? wq : (j == 1) ? wk : (j == 2) ? wv : wo;
        dst = (j == 0) ? wqb : (j == 1) ? wkb : (j == 2) ? wvb : wob;
    }
    float4 v = *(const float4*)(src + off);
    ushort4 o;
    o.x = f2bf(v.x); o.y = f2bf(v.y); o.z = f2bf(v.z); o.w = f2bf(v.w);
    *(ushort4*)(dst + off) = o;
}

// ---------------------------------------------------------------------------
// GEMM body: C[M,Nc] = A[M,K](bf16) @ W[Nc,K]^T(bf16) + bias
// ---------------------------------------------------------------------------
template<int OUT_MODE>
__device__ __forceinline__ void gemm_body(
    unsigned short* __restrict__ As, unsigned short* __restrict__ Bs,
    const unsigned short* __restrict__ A, const unsigned short* __restrict__ W,
    const float* __restrict__ bias, void* __restrict__ Cout, int bx, int by)
{
    constexpr int K = D_;
    const int tid  = threadIdx.x;
    const int lane = tid & 63;
    const int wave = tid >> 6;
    const int wm = wave & 1, wn = wave >> 1;
    const int l15 = lane & 15, quad = lane >> 4;

    f32x4 acc[4][4] = {};
    const int row0 = by * 128, col0 = bx * 128;

    const int srow = lane >> 3;   // row within 1KB chunk (8 rows x 128B)
    const int scb  = lane & 7;    // 16B block within row

    for (int k0 = 0; k0 < K; k0 += 64) {
        __syncthreads();
#pragma unroll
        for (int cc = 0; cc < 4; ++cc) {       // 16 chunks / 4 waves
            int c  = wave * 4 + cc;
            int lr = c * 8 + srow;             // tile row 0..127
            int gcol = k0 + ((scb ^ (lr & 7)) * 8);
            async_load16(A + (size_t)(row0 + lr) * K + gcol, As + c * 512);
            async_load16(W + (size_t)(col0 + lr) * K + gcol, Bs + c * 512);
        }
        __syncthreads();

#pragma unroll
        for (int kf = 0; kf < 2; ++kf) {
            const int swz = ((kf * 4 + quad) ^ (l15 & 7)) * 8;
            short8 af[4], bf[4];
#pragma unroll
            for (int mi = 0; mi < 4; mi++)
                af[mi] = *(const short8*)(&As[(wm * 64 + mi * 16 + l15) * 64 + swz]);
#pragma unroll
            for (int ni = 0; ni < 4; ni++)
                bf[ni] = *(const short8*)(&Bs[(wn * 64 + ni * 16 + l15) * 64 + swz]);
#pragma unroll
            for (int mi = 0; mi < 4; mi++)
#pragma unroll
                for (int ni = 0; ni < 4; ni++)
                    acc[mi][ni] = __builtin_amdgcn_mfma_f32_16x16x32_bf16(
                        af[mi], bf[ni], acc[mi][ni], 0, 0, 0);
        }
    }

#pragma unroll
    for (int ni = 0; ni < 4; ni++) {
        int col = col0 + wn * 64 + ni * 16 + l15;
        float bv = bias[col];
#pragma unroll
        for (int mi = 0; mi < 4; mi++) {
            int row = row0 + wm * 64 + mi * 16 + quad * 4;
            if (OUT_MODE == 2) {
                ushort4 pk;
                pk.x = f2bf(acc[mi][ni][0] + bv);
                pk.y = f2bf(acc[mi][ni][1] + bv);
                pk.z = f2bf(acc[mi][ni][2] + bv);
                pk.w = f2bf(acc[mi][ni][3] + bv);
                *(ushort4*)((unsigned short*)Cout + (size_t)col * BN_ + row) = pk;
            } else {
#pragma unroll
                for (int r = 0; r < 4; r++) {
                    float v = acc[mi][ni][r] + bv;
                    if (OUT_MODE == 3) v *= QSCL;
                    if (OUT_MODE == 0)
                        ((float*)Cout)[(size_t)(row + r) * D_ + col] = v;
                    else
                        ((unsigned short*)Cout)[(size_t)(row + r) * D_ + col] = f2bf(v);
                }
            }
        }
    }
}

// XCD-aware bijective block swizzle (T1). nwg = 8*32 = 256, nwg%8==0.
// HW assigns dispatch-flat index d to XCD d%8; remap so each XCD gets a
// contiguous chunk of work ids: 4 consecutive M-panels x all 8 N-panels
// (unique L2 footprint ~1 MB A + 2 MB W < 4 MB per-XCD L2).
__device__ __forceinline__ void xcd_swz(int& bx, int& by) {
    int w = blockIdx.y * 8 + blockIdx.x;      // dispatch-flat (x fastest)
    int s = (w & 7) * 32 + (w >> 3);          // bijective transpose, nwg=256
    bx = s & 7; by = s >> 3;
}

// Kernel 2: fused QKV projection (z selects q/k/v; q pre-scaled, v transposed)
__global__ __launch_bounds__(256) void qkv_gemm(
    const unsigned short* __restrict__ xb,
    const unsigned short* __restrict__ wqb, const unsigned short* __restrict__ wkb,
    const unsigned short* __restrict__ wvb,
    const float* __restrict__ bq, const float* __restrict__ bk, const float* __restrict__ bv,
    unsigned short* __restrict__ q, unsigned short* __restrict__ k, unsigned short* __restrict__ vt)
{
    __shared__ __align__(16) unsigned short As[128 * 64];   // 16 KB — shared by all
    __shared__ __align__(16) unsigned short Bs[128 * 64];   // 16 KB   three branches
    int bx, by; xcd_swz(bx, by);
    if (blockIdx.z == 0)
        gemm_body<3>(As, Bs, xb, wqb, bq, q,  bx, by);
    else if (blockIdx.z == 1)
        gemm_body<1>(As, Bs, xb, wkb, bk, k,  bx, by);
    else
        gemm_body<2>(As, Bs, xb, wvb, bv, vt, bx, by);
}

// Kernel 4: output projection, fp32 out
__global__ __launch_bounds__(256) void out_gemm(
    const unsigned short* __restrict__ attn, const unsigned short* __restrict__ wob,
    const float* __restrict__ bo, float* __restrict__ out)
{
    __shared__ __align__(16) unsigned short As[128 * 64];
    __shared__ __align__(16) unsigned short Bs[128 * 64];
    int bx, by; xcd_swz(bx, by);
    gemm_body<0>(As, Bs, attn, wob, bo, out, bx, by);
}

// ---------------------------------------------------------------------------
// Kernel 3a: flash attention, KV-SPLIT x NS (R6: NS=4 preferred).
// R5 post-mortem: occupancy 18->30% bought -20% time; still latency-bound
// (VALU 46 / MFMA 26 / HBM 15%, nothing saturated). LDS 32 KB/block allows
// 5 blocks/CU; NS=4 supplies 2048 blocks so residency can reach the cap.
// Inner loop identical to the R5-verified body.
// ---------------------------------------------------------------------------
template<int NS>
__global__ __launch_bounds__(256, 4) void attn_split(
    const unsigned short* __restrict__ q, const unsigned short* __restrict__ k,
    const unsigned short* __restrict__ vt,
    float* __restrict__ opart, float* __restrict__ lspart)
{
    __shared__ __align__(16) unsigned short Ks[2][64 * 64];   // 16 KB dbuf [kv][dh]
    __shared__ __align__(16) unsigned short Vs[2][64 * 64];   // 16 KB dbuf [dh][kv]

    const int tid = threadIdx.x;
    const int lane = tid & 63, wave = tid >> 6;
    const int l31 = lane & 31, kq = lane >> 5;
    const int bh = blockIdx.x;        // b*H + h — FAST index: XCD = bh%8
    const int qt = blockIdx.y;        // Q tile (0..15), 128 rows
    const int z  = blockIdx.z;        // KV slice (0..NS-1)
    const int b = bh >> 4, h = bh & 15;

    const unsigned short* qb = q  + (size_t)b * N_ * D_ + h * DH_;
    const unsigned short* kb = k  + (size_t)b * N_ * D_ + h * DH_;
    const unsigned short* vb = vt + (size_t)h * DH_ * BN_ + (size_t)b * N_;  // vt[h*64+dh][b*N+n]

    const int qrow0 = qt * 128 + wave * 32;
    const int kvbase = z * (N_ / NS);

    // Q B-frags (pre-scaled): lane l31 holds Q[qrow0+l31][s*16 + kq*8 .. +7]
    short8 qf[4];
#pragma unroll
    for (int s = 0; s < 4; s++)
        qf[s] = *(const short8*)(qb + (size_t)(qrow0 + l31) * D_ + s * 16 + kq * 8);

    f32x16 oacc[2] = {};   // O[qrow][dh] (32x32 C-layout), nb = dh-half
    float lsum = 0.f;      // running row-sum for qrow = l31 (this lane's kv share)

    const int srow = lane >> 3, scb = lane & 7;

    // stage K/V tile kv0 into buffer bi (2 async chunks each per wave)
    auto stage = [&](int bi, int kv0) {
#pragma unroll
        for (int cc = 0; cc < 2; ++cc) {
            int c  = wave * 2 + cc;
            int lr = c * 8 + srow;             // 0..63
            int swz8 = (scb ^ (lr & 7)) * 8;
            async_load16(kb + (size_t)(kv0 + lr) * D_ + swz8, (unsigned short*)Ks[bi] + c * 512);
            async_load16(vb + (size_t)lr * BN_ + kv0 + swz8,  (unsigned short*)Vs[bi] + c * 512);
        }
    };

    stage(0, kvbase);   // prologue

    const int NIT = (N_ / NS) / 64;
    for (int it = 0; it < NIT; ++it) {
        const int cur = it & 1;
        __syncthreads();   // drains vmcnt -> buf[cur] ready; buf[cur^1] readers done
        if (it + 1 < NIT) stage(cur ^ 1, kvbase + (it + 1) * 64);   // prefetch next

        const unsigned short* Kc = Ks[cur];
        const unsigned short* Vc = Vs[cur];

        // sequential kv-halves: QK^T -> exp2/pack -> PV for mb, then mb+1
#pragma unroll
        for (int mb = 0; mb < 2; mb++) {
            f32x16 st = {};
#pragma unroll
            for (int s = 0; s < 4; s++) {
                short8 kfr = *(const short8*)((const char*)Kc +
                    (mb * 32 + l31) * 128 + (((2 * s + kq) ^ (l31 & 7)) * 16));
                st = __builtin_amdgcn_mfma_f32_32x32x16_bf16(kfr, qf[s], st, 0, 0, 0);
            }

            unsigned int pk[8];
#pragma unroll
            for (int g = 0; g < 4; g++) {
                float p0 = EXP2(st[g * 4 + 0]);
                float p1 = EXP2(st[g * 4 + 1]);
                float p2 = EXP2(st[g * 4 + 2]);
                float p3 = EXP2(st[g * 4 + 3]);
                lsum += (p0 + p1) + (p2 + p3);
                pk[2 * g + 0] = pkbf(p0, p1);
                pk[2 * g + 1] = pkbf(p2, p3);
            }
#pragma unroll
            for (int s = 0; s < 2; s++) {
                uint4v fu;
                fu[0] = pk[4 * s + 0]; fu[1] = pk[4 * s + 1];
                fu[2] = pk[4 * s + 2]; fu[3] = pk[4 * s + 3];
                short8 pf = __builtin_bit_cast(short8, fu);
                const int blkA = 4 * mb + 2 * s;
#pragma unroll
                for (int nb = 0; nb < 2; nb++) {
                    const char* vrow = (const char*)Vc + (nb * 32 + l31) * 128;
                    uint2 vlo = *(const uint2*)(vrow + ((blkA       ^ (l31 & 7)) * 16) + kq * 8);
                    uint2 vhi = *(const uint2*)(vrow + (((blkA + 1) ^ (l31 & 7)) * 16) + kq * 8);
                    uint4v vu; vu[0] = vlo.x; vu[1] = vlo.y; vu[2] = vhi.x; vu[3] = vhi.y;
                    short8 vf = __builtin_bit_cast(short8, vu);
                    oacc[nb] = __builtin_amdgcn_mfma_f32_32x32x16_bf16(
                        pf, vf, oacc[nb], 0, 0, 0);
                }
            }
        }
    }

    // ---- partial epilogue: raw fp32 O + per-row lsum, NO normalization ----
    lsum += __shfl_xor(lsum, 32);          // full row sum for this slice
    if (kq == 0)
        lspart[(size_t)z * (32 * 2048) + ((size_t)bh << 11) + qrow0 + l31] = lsum;

    float* op = opart + (size_t)z * ((size_t)BN_ * D_);
#pragma unroll
    for (int g = 0; g < 4; g++)
#pragma unroll
        for (int rr = 0; rr < 4; rr++) {
            int reg = g * 4 + rr;
            int row = qrow0 + rr + 8 * g + 4 * kq;
            size_t base = ((size_t)b * N_ + row) * D_ + h * DH_;
#pragma unroll
            for (int nb = 0; nb < 2; nb++)
                op[base + nb * 32 + l31] = oacc[nb][reg];
        }
}

// Kernel 3b: combine KV-split partials -> normalized bf16 attention output
template<int NS>
__global__ __launch_bounds__(256) void combine_kernel(
    const float* __restrict__ opart, const float* __restrict__ lspart,
    unsigned short* __restrict__ ad)
{
    const size_t HALF = (size_t)BN_ * D_;   // 4194304 floats per z
    size_t i = ((size_t)blockIdx.x * 256 + threadIdx.x) * 4;
    int bn = (int)(i >> 10);               // b*N + n  (0..4095)
    int h  = (int)((i >> 6) & 15);
    int b  = bn >> 11, n = bn & 2047;
    float4 a = *(const float4*)(opart + i);
    float l;
    {
        size_t li = (((size_t)(b * 16 + h)) << 11) + n;
        l = lspart[li];
#pragma unroll
        for (int z = 1; z < NS; z++) l += lspart[li + (size_t)z * (32 * 2048)];
    }
#pragma unroll
    for (int z = 1; z < NS; z++) {
        float4 c = *(const float4*)(opart + (size_t)z * HALF + i);
        a.x += c.x; a.y += c.y; a.z += c.z; a.w += c.w;
    }
    float inv = 1.f / l;
    ushort4 r;
    r.x = f2bf(a.x * inv);
    r.y = f2bf(a.y * inv);
    r.z = f2bf(a.z * inv);
    r.w = f2bf(a.w * inv);
    *(ushort4*)(ad + i) = r;
}

// ---------------------------------------------------------------------------
// Kernel 3 (fallback): R3-verified single-pass attention (used if ws_size
// cannot hold any split partials).
// ---------------------------------------------------------------------------
__global__ __launch_bounds__(256) void attn_kernel(
    const unsigned short* __restrict__ q, const unsigned short* __restrict__ k,
    const unsigned short* __restrict__ vt, unsigned short* __restrict__ o)
{
    __shared__ __align__(16) unsigned short Ks[2][64 * 64];
    __shared__ __align__(16) unsigned short Vs[2][64 * 64];

    const int tid = threadIdx.x;
    const int lane = tid & 63, wave = tid >> 6;
    const int l31 = lane & 31, kq = lane >> 5;
    const int bh = blockIdx.x;
    const int qt = blockIdx.y;
    const int b = bh >> 4, h = bh & 15;

    const unsigned short* qb = q  + (size_t)b * N_ * D_ + h * DH_;
    const unsigned short* kb = k  + (size_t)b * N_ * D_ + h * DH_;
    const unsigned short* vb = vt + (size_t)h * DH_ * BN_ + (size_t)b * N_;

    const int qrow0 = qt * 128 + wave * 32;

    short8 qf[4];
#pragma unroll
    for (int s = 0; s < 4; s++)
        qf[s] = *(const short8*)(qb + (size_t)(qrow0 + l31) * D_ + s * 16 + kq * 8);

    f32x16 oacc[2] = {};
    float lsum = 0.f;

    const int srow = lane >> 3, scb = lane & 7;

    auto stage = [&](int bi, int kv0) {
#pragma unroll
        for (int cc = 0; cc < 2; ++cc) {
            int c  = wave * 2 + cc;
            int lr = c * 8 + srow;
            int swz8 = (scb ^ (lr & 7)) * 8;
            async_load16(kb + (size_t)(kv0 + lr) * D_ + swz8, (unsigned short*)Ks[bi] + c * 512);
            async_load16(vb + (size_t)lr * BN_ + kv0 + swz8,  (unsigned short*)Vs[bi] + c * 512);
        }
    };

    stage(0, 0);

    const int NIT = N_ / 64;
    for (int it = 0; it < NIT; ++it) {
        const int cur = it & 1;
        __syncthreads();
        if (it + 1 < NIT) stage(cur ^ 1, (it + 1) * 64);

        const unsigned short* Kc = Ks[cur];
        const unsigned short* Vc = Vs[cur];

        f32x16 st[2] = {};
#pragma unroll
        for (int s = 0; s < 4; s++) {
#pragma unroll
            for (int mb = 0; mb < 2; mb++) {
                short8 kfr = *(const short8*)((const char*)Kc +
                    (mb * 32 + l31) * 128 + (((2 * s + kq) ^ (l31 & 7)) * 16));
                st[mb] = __builtin_amdgcn_mfma_f32_32x32x16_bf16(
                    kfr, qf[s], st[mb], 0, 0, 0);
            }
        }

#pragma unroll
        for (int mb = 0; mb < 2; mb++) {
            unsigned int pk[8];
#pragma unroll
            for (int g = 0; g < 4; g++) {
                float p0 = EXP2(st[mb][g * 4 + 0]);
                float p1 = EXP2(st[mb][g * 4 + 1]);
                float p2 = EXP2(st[mb][g * 4 + 2]);
                float p3 = EXP2(st[mb][g * 4 + 3]);
                lsum += (p0 + p1) + (p2 + p3);
                pk[2 * g + 0] = pkbf(p0, p1);
                pk[2 * g + 1] = pkbf(p2, p3);
            }
#pragma unroll
            for (int s = 0; s < 2; s++) {
                uint4v fu;
                fu[0] = pk[4 * s + 0]; fu[1] = pk[4 * s + 1];
                fu[2] = pk[4 * s + 2]; fu[3] = pk[4 * s + 3];
                short8 pf = __builtin_bit_cast(short8, fu);
                const int blkA = 4 * mb + 2 * s;
#pragma unroll
                for (int nb = 0; nb < 2; nb++) {
                    const char* vrow = (const char*)Vc + (nb * 32 + l31) * 128;
                    uint2 vlo = *(const uint2*)(vrow + ((blkA       ^ (l31 & 7)) * 16) + kq * 8);
                    uint2 vhi = *(const uint2*)(vrow + (((blkA + 1) ^ (l31 & 7)) * 16) + kq * 8);
                    uint4v vu; vu[0] = vlo.x; vu[1] = vlo.y; vu[2] = vhi.x; vu[3] = vhi.y;
                    short8 vf = __builtin_bit_cast(short8, vu);
                    oacc[nb] = __builtin_amdgcn_mfma_f32_32x32x16_bf16(
                        pf, vf, oacc[nb], 0, 0, 0);
                }
            }
        }
    }

    lsum += __shfl_xor(lsum, 32);
    __syncthreads();
    float* Lt = (float*)&Ks[0][0] + wave * 32;
    if (kq == 0) Lt[l31] = lsum;
    asm volatile("s_waitcnt lgkmcnt(0)" ::: "memory");

#pragma unroll
    for (int g = 0; g < 4; g++)
#pragma unroll
        for (int rr = 0; rr < 4; rr++) {
            int reg = g * 4 + rr;
            float inv = 1.f / Lt[rr + 8 * g + 4 * kq];
            int row = qrow0 + rr + 8 * g + 4 * kq;
            size_t base = ((size_t)b * N_ + row) * D_ + h * DH_;
#pragma unroll
            for (int nb = 0; nb < 2; nb++)
                o[base + nb * 32 + l31] = f2bf(oacc[nb][reg] * inv);
        }
}

// ---------------------------------------------------------------------------
extern "C" void kernel_launch(void* const* d_in, const int* in_sizes, int n_in,
                              void* d_out, int out_size, void* d_ws, size_t ws_size,
                              hipStream_t stream)
{
    const float* x  = (const float*)d_in[0];
    const float* Wq = (const float*)d_in[1];
    const float* bq = (const float*)d_in[2];
    const float* Wk = (const float*)d_in[3];
    const float* bk = (const float*)d_in[4];
    const float* Wv = (const float*)d_in[5];
    const float* bv = (const float*)d_in[6];
    const float* Wo = (const float*)d_in[7];
    const float* bo = (const float*)d_in[8];
    float* out = (float*)d_out;

    char* ws = (char*)d_ws;
    unsigned short* xb  = (unsigned short*)(ws + 0);         //  8 MB  x bf16
    unsigned short* wqb = (unsigned short*)(ws + 8388608);   //  2 MB
    unsigned short* wkb = (unsigned short*)(ws + 10485760);  //  2 MB
    unsigned short* wvb = (unsigned short*)(ws + 12582912);  //  2 MB
    unsigned short* wob = (unsigned short*)(ws + 14680064);  //  2 MB
    unsigned short* qd  = (unsigned short*)(ws + 16777216);  //  8 MB  Q (pre-scaled)
    unsigned short* kd  = (unsigned short*)(ws + 25165824);  //  8 MB
    unsigned short* vtd = (unsigned short*)(ws + 33554432);  //  8 MB  V^T [D][B*N]
    unsigned short* ad  = (unsigned short*)(ws + 41943040);  //  8 MB  attn out
    // base total 48 MB. Split partials:
    //   NS=4: opart 48..112 MB (4x16 MB), lsw 112..113 MB  -> need 118489088
    //   NS=2: opart 48..80 MB  (2x16 MB), lsw 80..80.5 MB  -> need  84410368
    float* opart = (float*)(ws + 50331648);
    float* lsw4  = (float*)(ws + 117440512);
    float* lsw2  = (float*)(ws + 83886080);
    const size_t WS_NEED4 = 118489088;
    const size_t WS_NEED2 = 84410368;

    cast_kernel<<<8192, 256, 0, stream>>>(x, Wq, Wk, Wv, Wo, xb, wqb, wkb, wvb, wob);
    qkv_gemm<<<dim3(8, 32, 3), 256, 0, stream>>>(xb, wqb, wkb, wvb, bq, bk, bv, qd, kd, vtd);
    if (ws_size >= WS_NEED4) {
        attn_split<4><<<dim3(32, 16, 4), 256, 0, stream>>>(qd, kd, vtd, opart, lsw4);
        combine_kernel<4><<<4096, 256, 0, stream>>>(opart, lsw4, ad);
    } else if (ws_size >= WS_NEED2) {
        attn_split<2><<<dim3(32, 16, 2), 256, 0, stream>>>(qd, kd, vtd, opart, lsw2);
        combine_kernel<2><<<4096, 256, 0, stream>>>(opart, lsw2, ad);
    } else {
        attn_kernel<<<dim3(32, 16), 256, 0, stream>>>(qd, kd, vtd, ad);
    }
    out_gemm<<<dim3(8, 32), 256, 0, stream>>>(ad, wob, bo, out);
}

// Round 7
// 204.388 us; speedup vs baseline: 1.0546x; 1.0546x over previous
//
#include <hip/hip_runtime.h>
#include <hip/hip_bf16.h>

// Problem constants
#define B_  2
#define N_  2048
#define D_  1024
#define H_  16
#define DH_ 64
#define BN_ (B_*N_)   // 4096 rows total

typedef __attribute__((ext_vector_type(8))) short short8;    // 8 bf16 (K=16/32 A/B frag)
typedef __attribute__((ext_vector_type(4))) float f32x4;     // 16x16 C/D frag
typedef __attribute__((ext_vector_type(16))) float f32x16;   // 32x32 C/D frag
typedef __attribute__((ext_vector_type(4))) unsigned int uint4v;

typedef __attribute__((address_space(3))) unsigned int lds_u32_t;
typedef const __attribute__((address_space(1))) unsigned int glb_u32_t;

// async global->LDS, 16B per lane; LDS dst = (wave-uniform base) + lane*16
__device__ __forceinline__ void async_load16(const unsigned short* g, unsigned short* l) {
    __builtin_amdgcn_global_load_lds((glb_u32_t*)g, (lds_u32_t*)l, 16, 0, 0);
}

__device__ __forceinline__ unsigned short f2bf(float f) {
    __hip_bfloat16 h = __float2bfloat16(f);
    return *reinterpret_cast<unsigned short*>(&h);
}

// pack bf16(a) low16 | bf16(b) high16; round-half-up + one v_perm_b32
__device__ __forceinline__ unsigned int pkbf(float a, float b) {
    unsigned int ua = __float_as_uint(a) + 0x8000u;
    unsigned int ub = __float_as_uint(b) + 0x8000u;
    return __builtin_amdgcn_perm(ub, ua, 0x07060302);
}

#if __has_builtin(__builtin_amdgcn_exp2f)
#define EXP2(x) __builtin_amdgcn_exp2f(x)
#else
#define EXP2(x) exp2f(x)
#endif

// softmax scale folded into Q projection: 1/sqrt(DH) * log2(e)
#define QSCL 0.1803368801111204f

// ---------------------------------------------------------------------------
// Kernel 1: cast fp32 -> bf16 for x, Wq, Wk, Wv, Wo (one fused launch)
// ---------------------------------------------------------------------------
__global__ __launch_bounds__(256) void cast_kernel(
    const float* __restrict__ x,  const float* __restrict__ wq,
    const float* __restrict__ wk, const float* __restrict__ wv,
    const float* __restrict__ wo,
    unsigned short* __restrict__ xb,  unsigned short* __restrict__ wqb,
    unsigned short* __restrict__ wkb, unsigned short* __restrict__ wvb,
    unsigned short* __restrict__ wob)
{
    const size_t NX = (size_t)BN_ * D_;   // 4194304
    const size_t NW = (size_t)D_ * D_;    // 1048576 (pow2)
    size_t i = ((size_t)blockIdx.x * 256 + threadIdx.x) * 4;
    const float* src; unsigned short* dst; size_t off;
    if (i < NX) { src = x; dst = xb; off = i; }
    else {
        size_t j = (i - NX) >> 20;          // which W
        off = (i - NX) & (NW - 1);
        src = (j == 0) ? wq : (j == 1) ? wk : (j == 2) ? wv : wo;
        dst = (j == 0) ? wqb : (j == 1) ? wkb : (j == 2) ? wvb : wob;
    }
    float4 v = *(const float4*)(src + off);
    ushort4 o;
    o.x = f2bf(v.x); o.y = f2bf(v.y); o.z = f2bf(v.z); o.w = f2bf(v.w);
    *(ushort4*)(dst + off) = o;
}

// ---------------------------------------------------------------------------
// GEMM body: C[M,Nc] = A[M,K](bf16) @ W[Nc,K]^T(bf16) + bias
// OUT_MODE 2 (V^T) now stages the 128x128 output tile in LDS (reusing As/Bs,
// dead after the K-loop) and writes coalesced 16B runs along BN — the old
// direct path stored 8B ushort4 at 8KB stride (~8x HBM write amplification).
// LDS tile uses r ^ ((c&7)<<3) XOR swizzle to break the 256B-stride bank
// pattern on both store and read sides.
// ---------------------------------------------------------------------------
template<int OUT_MODE>
__device__ __forceinline__ void gemm_body(
    unsigned short* __restrict__ As, unsigned short* __restrict__ Bs,
    const unsigned short* __restrict__ A, const unsigned short* __restrict__ W,
    const float* __restrict__ bias, void* __restrict__ Cout, int bx, int by)
{
    constexpr int K = D_;
    const int tid  = threadIdx.x;
    const int lane = tid & 63;
    const int wave = tid >> 6;
    const int wm = wave & 1, wn = wave >> 1;
    const int l15 = lane & 15, quad = lane >> 4;

    f32x4 acc[4][4] = {};
    const int row0 = by * 128, col0 = bx * 128;

    const int srow = lane >> 3;   // row within 1KB chunk (8 rows x 128B)
    const int scb  = lane & 7;    // 16B block within row

    for (int k0 = 0; k0 < K; k0 += 64) {
        __syncthreads();
#pragma unroll
        for (int cc = 0; cc < 4; ++cc) {       // 16 chunks / 4 waves
            int c  = wave * 4 + cc;
            int lr = c * 8 + srow;             // tile row 0..127
            int gcol = k0 + ((scb ^ (lr & 7)) * 8);
            async_load16(A + (size_t)(row0 + lr) * K + gcol, As + c * 512);
            async_load16(W + (size_t)(col0 + lr) * K + gcol, Bs + c * 512);
        }
        __syncthreads();

#pragma unroll
        for (int kf = 0; kf < 2; ++kf) {
            const int swz = ((kf * 4 + quad) ^ (l15 & 7)) * 8;
            short8 af[4], bf[4];
#pragma unroll
            for (int mi = 0; mi < 4; mi++)
                af[mi] = *(const short8*)(&As[(wm * 64 + mi * 16 + l15) * 64 + swz]);
#pragma unroll
            for (int ni = 0; ni < 4; ni++)
                bf[ni] = *(const short8*)(&Bs[(wn * 64 + ni * 16 + l15) * 64 + swz]);
#pragma unroll
            for (int mi = 0; mi < 4; mi++)
#pragma unroll
                for (int ni = 0; ni < 4; ni++)
                    acc[mi][ni] = __builtin_amdgcn_mfma_f32_16x16x32_bf16(
                        af[mi], bf[ni], acc[mi][ni], 0, 0, 0);
        }
    }

    if (OUT_MODE == 2) {
        // ---- V^T epilogue: LDS transpose staging, coalesced global write ----
        __syncthreads();   // all waves done reading As/Bs from the last tile
#pragma unroll
        for (int ni = 0; ni < 4; ni++) {
            int c = wn * 64 + ni * 16 + l15;          // local col 0..127
            float bv = bias[col0 + c];
#pragma unroll
            for (int mi = 0; mi < 4; mi++) {
                int r = wm * 64 + mi * 16 + quad * 4; // local row, multiple of 4
                ushort4 pk;
                pk.x = f2bf(acc[mi][ni][0] + bv);
                pk.y = f2bf(acc[mi][ni][1] + bv);
                pk.z = f2bf(acc[mi][ni][2] + bv);
                pk.w = f2bf(acc[mi][ni][3] + bv);
                unsigned short* base = (c < 64) ? (As + c * 128) : (Bs + (c - 64) * 128);
                *(ushort4*)(base + (r ^ ((c & 7) << 3))) = pk;  // XOR swz (bits 3-5)
            }
        }
        __syncthreads();
        // cooperative coalesced write: 2048 items = 128 cols x 16 row-blocks(16B)
#pragma unroll
        for (int itx = 0; itx < 8; ++itx) {
            int item = itx * 256 + tid;
            int c  = item >> 4;        // 0..127 (16 consecutive lanes share c)
            int rb = item & 15;        // logical 8-elem row block
            const unsigned short* base = (c < 64) ? (As + c * 128) : (Bs + (c - 64) * 128);
            uint4v v = *(const uint4v*)(base + ((rb ^ (c & 7)) * 8));
            *(uint4v*)((unsigned short*)Cout + (size_t)(col0 + c) * BN_ + row0 + rb * 8) = v;
        }
        return;
    }

#pragma unroll
    for (int ni = 0; ni < 4; ni++) {
        int col = col0 + wn * 64 + ni * 16 + l15;
        float bv = bias[col];
#pragma unroll
        for (int mi = 0; mi < 4; mi++) {
            int row = row0 + wm * 64 + mi * 16 + quad * 4;
#pragma unroll
            for (int r = 0; r < 4; r++) {
                float v = acc[mi][ni][r] + bv;
                if (OUT_MODE == 3) v *= QSCL;
                if (OUT_MODE == 0)
                    ((float*)Cout)[(size_t)(row + r) * D_ + col] = v;
                else
                    ((unsigned short*)Cout)[(size_t)(row + r) * D_ + col] = f2bf(v);
            }
        }
    }
}

// XCD-aware bijective block swizzle (T1). nwg = 8*32 = 256, nwg%8==0.
// Remap so each XCD gets 4 consecutive M-panels x all 8 N-panels
// (unique L2 footprint ~1 MB A + 2 MB W < 4 MB per-XCD L2).
__device__ __forceinline__ void xcd_swz(int& bx, int& by) {
    int w = blockIdx.y * 8 + blockIdx.x;      // dispatch-flat (x fastest)
    int s = (w & 7) * 32 + (w >> 3);          // bijective transpose, nwg=256
    bx = s & 7; by = s >> 3;
}

// Kernel 2: fused QKV projection (z selects q/k/v; q pre-scaled, v transposed)
__global__ __launch_bounds__(256) void qkv_gemm(
    const unsigned short* __restrict__ xb,
    const unsigned short* __restrict__ wqb, const unsigned short* __restrict__ wkb,
    const unsigned short* __restrict__ wvb,
    const float* __restrict__ bq, const float* __restrict__ bk, const float* __restrict__ bv,
    unsigned short* __restrict__ q, unsigned short* __restrict__ k, unsigned short* __restrict__ vt)
{
    __shared__ __align__(16) unsigned short As[128 * 64];   // 16 KB — shared by all
    __shared__ __align__(16) unsigned short Bs[128 * 64];   // 16 KB   three branches
    int bx, by; xcd_swz(bx, by);
    if (blockIdx.z == 0)
        gemm_body<3>(As, Bs, xb, wqb, bq, q,  bx, by);
    else if (blockIdx.z == 1)
        gemm_body<1>(As, Bs, xb, wkb, bk, k,  bx, by);
    else
        gemm_body<2>(As, Bs, xb, wvb, bv, vt, bx, by);
}

// Kernel 4: output projection, fp32 out
__global__ __launch_bounds__(256) void out_gemm(
    const unsigned short* __restrict__ attn, const unsigned short* __restrict__ wob,
    const float* __restrict__ bo, float* __restrict__ out)
{
    __shared__ __align__(16) unsigned short As[128 * 64];
    __shared__ __align__(16) unsigned short Bs[128 * 64];
    int bx, by; xcd_swz(bx, by);
    gemm_body<0>(As, Bs, attn, wob, bo, out, bx, by);
}

// ---------------------------------------------------------------------------
// Kernel 3: flash attention — R3-verified single-pass (best TOTAL config:
// R3 208.1 vs split 215.3/215.5 — combine + fp32 partial traffic ate the
// split's attn gain; reverted). 128 Q-rows/block, 4 waves, full KV,
// full-rate 32x32x16 PV with in-lane P frags + kq-split b64 V reads.
// ---------------------------------------------------------------------------
__global__ __launch_bounds__(256) void attn_kernel(
    const unsigned short* __restrict__ q, const unsigned short* __restrict__ k,
    const unsigned short* __restrict__ vt, unsigned short* __restrict__ o)
{
    __shared__ __align__(16) unsigned short Ks[2][64 * 64];
    __shared__ __align__(16) unsigned short Vs[2][64 * 64];

    const int tid = threadIdx.x;
    const int lane = tid & 63, wave = tid >> 6;
    const int l31 = lane & 31, kq = lane >> 5;
    const int bh = blockIdx.x;
    const int qt = blockIdx.y;
    const int b = bh >> 4, h = bh & 15;

    const unsigned short* qb = q  + (size_t)b * N_ * D_ + h * DH_;
    const unsigned short* kb = k  + (size_t)b * N_ * D_ + h * DH_;
    const unsigned short* vb = vt + (size_t)h * DH_ * BN_ + (size_t)b * N_;

    const int qrow0 = qt * 128 + wave * 32;

    short8 qf[4];
#pragma unroll
    for (int s = 0; s < 4; s++)
        qf[s] = *(const short8*)(qb + (size_t)(qrow0 + l31) * D_ + s * 16 + kq * 8);

    f32x16 oacc[2] = {};
    float lsum = 0.f;

    const int srow = lane >> 3, scb = lane & 7;

    auto stage = [&](int bi, int kv0) {
#pragma unroll
        for (int cc = 0; cc < 2; ++cc) {
            int c  = wave * 2 + cc;
            int lr = c * 8 + srow;
            int swz8 = (scb ^ (lr & 7)) * 8;
            async_load16(kb + (size_t)(kv0 + lr) * D_ + swz8, (unsigned short*)Ks[bi] + c * 512);
            async_load16(vb + (size_t)lr * BN_ + kv0 + swz8,  (unsigned short*)Vs[bi] + c * 512);
        }
    };

    stage(0, 0);

    const int NIT = N_ / 64;
    for (int it = 0; it < NIT; ++it) {
        const int cur = it & 1;
        __syncthreads();
        if (it + 1 < NIT) stage(cur ^ 1, (it + 1) * 64);

        const unsigned short* Kc = Ks[cur];
        const unsigned short* Vc = Vs[cur];

        f32x16 st[2] = {};
#pragma unroll
        for (int s = 0; s < 4; s++) {
#pragma unroll
            for (int mb = 0; mb < 2; mb++) {
                short8 kfr = *(const short8*)((const char*)Kc +
                    (mb * 32 + l31) * 128 + (((2 * s + kq) ^ (l31 & 7)) * 16));
                st[mb] = __builtin_amdgcn_mfma_f32_32x32x16_bf16(
                    kfr, qf[s], st[mb], 0, 0, 0);
            }
        }

#pragma unroll
        for (int mb = 0; mb < 2; mb++) {
            unsigned int pk[8];
#pragma unroll
            for (int g = 0; g < 4; g++) {
                float p0 = EXP2(st[mb][g * 4 + 0]);
                float p1 = EXP2(st[mb][g * 4 + 1]);
                float p2 = EXP2(st[mb][g * 4 + 2]);
                float p3 = EXP2(st[mb][g * 4 + 3]);
                lsum += (p0 + p1) + (p2 + p3);
                pk[2 * g + 0] = pkbf(p0, p1);
                pk[2 * g + 1] = pkbf(p2, p3);
            }
#pragma unroll
            for (int s = 0; s < 2; s++) {
                uint4v fu;
                fu[0] = pk[4 * s + 0]; fu[1] = pk[4 * s + 1];
                fu[2] = pk[4 * s + 2]; fu[3] = pk[4 * s + 3];
                short8 pf = __builtin_bit_cast(short8, fu);
                const int blkA = 4 * mb + 2 * s;
#pragma unroll
                for (int nb = 0; nb < 2; nb++) {
                    const char* vrow = (const char*)Vc + (nb * 32 + l31) * 128;
                    uint2 vlo = *(const uint2*)(vrow + ((blkA       ^ (l31 & 7)) * 16) + kq * 8);
                    uint2 vhi = *(const uint2*)(vrow + (((blkA + 1) ^ (l31 & 7)) * 16) + kq * 8);
                    uint4v vu; vu[0] = vlo.x; vu[1] = vlo.y; vu[2] = vhi.x; vu[3] = vhi.y;
                    short8 vf = __builtin_bit_cast(short8, vu);
                    oacc[nb] = __builtin_amdgcn_mfma_f32_32x32x16_bf16(
                        pf, vf, oacc[nb], 0, 0, 0);
                }
            }
        }
    }

    lsum += __shfl_xor(lsum, 32);
    __syncthreads();
    float* Lt = (float*)&Ks[0][0] + wave * 32;
    if (kq == 0) Lt[l31] = lsum;
    asm volatile("s_waitcnt lgkmcnt(0)" ::: "memory");

#pragma unroll
    for (int g = 0; g < 4; g++)
#pragma unroll
        for (int rr = 0; rr < 4; rr++) {
            int reg = g * 4 + rr;
            float inv = 1.f / Lt[rr + 8 * g + 4 * kq];
            int row = qrow0 + rr + 8 * g + 4 * kq;
            size_t base = ((size_t)b * N_ + row) * D_ + h * DH_;
#pragma unroll
            for (int nb = 0; nb < 2; nb++)
                o[base + nb * 32 + l31] = f2bf(oacc[nb][reg] * inv);
        }
}

// ---------------------------------------------------------------------------
extern "C" void kernel_launch(void* const* d_in, const int* in_sizes, int n_in,
                              void* d_out, int out_size, void* d_ws, size_t ws_size,
                              hipStream_t stream)
{
    const float* x  = (const float*)d_in[0];
    const float* Wq = (const float*)d_in[1];
    const float* bq = (const float*)d_in[2];
    const float* Wk = (const float*)d_in[3];
    const float* bk = (const float*)d_in[4];
    const float* Wv = (const float*)d_in[5];
    const float* bv = (const float*)d_in[6];
    const float* Wo = (const float*)d_in[7];
    const float* bo = (const float*)d_in[8];
    float* out = (float*)d_out;

    char* ws = (char*)d_ws;
    unsigned short* xb  = (unsigned short*)(ws + 0);         //  8 MB  x bf16
    unsigned short* wqb = (unsigned short*)(ws + 8388608);   //  2 MB
    unsigned short* wkb = (unsigned short*)(ws + 10485760);  //  2 MB
    unsigned short* wvb = (unsigned short*)(ws + 12582912);  //  2 MB
    unsigned short* wob = (unsigned short*)(ws + 14680064);  //  2 MB
    unsigned short* qd  = (unsigned short*)(ws + 16777216);  //  8 MB  Q (pre-scaled)
    unsigned short* kd  = (unsigned short*)(ws + 25165824);  //  8 MB
    unsigned short* vtd = (unsigned short*)(ws + 33554432);  //  8 MB  V^T [D][B*N]
    unsigned short* ad  = (unsigned short*)(ws + 41943040);  //  8 MB  attn out
    // total 48 MB

    cast_kernel<<<8192, 256, 0, stream>>>(x, Wq, Wk, Wv, Wo, xb, wqb, wkb, wvb, wob);
    qkv_gemm<<<dim3(8, 32, 3), 256, 0, stream>>>(xb, wqb, wkb, wvb, bq, bk, bv, qd, kd, vtd);
    attn_kernel<<<dim3(32, 16), 256, 0, stream>>>(qd, kd, vtd, ad);
    out_gemm<<<dim3(8, 32), 256, 0, stream>>>(ad, wob, bo, out);
}

// Round 8
// 203.165 us; speedup vs baseline: 1.0610x; 1.0060x over previous
//
#include <hip/hip_runtime.h>
#include <hip/hip_bf16.h>

// Problem constants
#define B_  2
#define N_  2048
#define D_  1024
#define H_  16
#define DH_ 64
#define BN_ (B_*N_)   // 4096 rows total

typedef __attribute__((ext_vector_type(8))) short short8;    // 8 bf16 (K=16/32 A/B frag)
typedef __attribute__((ext_vector_type(4))) float f32x4;     // 16x16 C/D frag
typedef __attribute__((ext_vector_type(16))) float f32x16;   // 32x32 C/D frag
typedef __attribute__((ext_vector_type(4))) unsigned int uint4v;

typedef __attribute__((address_space(3))) unsigned int lds_u32_t;
typedef const __attribute__((address_space(1))) unsigned int glb_u32_t;

// async global->LDS, 16B per lane; LDS dst = (wave-uniform base) + lane*16
__device__ __forceinline__ void async_load16(const unsigned short* g, unsigned short* l) {
    __builtin_amdgcn_global_load_lds((glb_u32_t*)g, (lds_u32_t*)l, 16, 0, 0);
}

__device__ __forceinline__ unsigned short f2bf(float f) {
    __hip_bfloat16 h = __float2bfloat16(f);
    return *reinterpret_cast<unsigned short*>(&h);
}

// pack bf16(a) low16 | bf16(b) high16; round-half-up + one v_perm_b32
__device__ __forceinline__ unsigned int pkbf(float a, float b) {
    unsigned int ua = __float_as_uint(a) + 0x8000u;
    unsigned int ub = __float_as_uint(b) + 0x8000u;
    return __builtin_amdgcn_perm(ub, ua, 0x07060302);
}

#if __has_builtin(__builtin_amdgcn_exp2f)
#define EXP2(x) __builtin_amdgcn_exp2f(x)
#else
#define EXP2(x) exp2f(x)
#endif

// softmax scale folded into Q projection: 1/sqrt(DH) * log2(e)
#define QSCL 0.1803368801111204f

// ---------------------------------------------------------------------------
// Kernel 1: cast fp32 -> bf16 for x, Wq, Wk, Wv, Wo (one fused launch)
// ---------------------------------------------------------------------------
__global__ __launch_bounds__(256) void cast_kernel(
    const float* __restrict__ x,  const float* __restrict__ wq,
    const float* __restrict__ wk, const float* __restrict__ wv,
    const float* __restrict__ wo,
    unsigned short* __restrict__ xb,  unsigned short* __restrict__ wqb,
    unsigned short* __restrict__ wkb, unsigned short* __restrict__ wvb,
    unsigned short* __restrict__ wob)
{
    const size_t NX = (size_t)BN_ * D_;   // 4194304
    const size_t NW = (size_t)D_ * D_;    // 1048576 (pow2)
    size_t i = ((size_t)blockIdx.x * 256 + threadIdx.x) * 4;
    const float* src; unsigned short* dst; size_t off;
    if (i < NX) { src = x; dst = xb; off = i; }
    else {
        size_t j = (i - NX) >> 20;          // which W
        off = (i - NX) & (NW - 1);
        src = (j == 0) ? wq : (j == 1) ? wk : (j == 2) ? wv : wo;
        dst = (j == 0) ? wqb : (j == 1) ? wkb : (j == 2) ? wvb : wob;
    }
    float4 v = *(const float4*)(src + off);
    ushort4 o;
    o.x = f2bf(v.x); o.y = f2bf(v.y); o.z = f2bf(v.z); o.w = f2bf(v.w);
    *(ushort4*)(dst + off) = o;
}

// ---------------------------------------------------------------------------
// GEMM body: C[M,Nc] = A[M,K](bf16) @ W[Nc,K]^T(bf16) + bias
// R8: double-buffered LDS + issue-before-compute (T3 minimum-2-phase, the
// same stage/dbuf/one-barrier pattern the attn kernel already validates).
// Old structure was stage -> barrier(vmcnt drain) -> compute: zero
// within-wave overlap, all waves lockstep -> out_gemm at 1 block/CU was
// pure serial stall. Now loads of tile t+1 fly during compute of tile t.
// As/Bs are each 2 x 8192 shorts (64 KB LDS total).
// OUT_MODE 2 (V^T) epilogue stages the output tile in the As region
// (32 KB contiguous) with XOR swizzle and writes coalesced 16B runs.
// ---------------------------------------------------------------------------
template<int OUT_MODE>
__device__ __forceinline__ void gemm_body(
    unsigned short* __restrict__ As, unsigned short* __restrict__ Bs,
    const unsigned short* __restrict__ A, const unsigned short* __restrict__ W,
    const float* __restrict__ bias, void* __restrict__ Cout, int bx, int by)
{
    constexpr int K = D_;
    constexpr int NT = K / 64;    // 16 K-tiles
    const int tid  = threadIdx.x;
    const int lane = tid & 63;
    const int wave = tid >> 6;
    const int wm = wave & 1, wn = wave >> 1;
    const int l15 = lane & 15, quad = lane >> 4;

    f32x4 acc[4][4] = {};
    const int row0 = by * 128, col0 = bx * 128;

    const int srow = lane >> 3;   // row within 1KB chunk (8 rows x 128B)
    const int scb  = lane & 7;    // 16B block within row

    auto stage = [&](int bi, int k0) {
        unsigned short* Ad = As + bi * 8192;
        unsigned short* Bd = Bs + bi * 8192;
#pragma unroll
        for (int cc = 0; cc < 4; ++cc) {       // 16 chunks / 4 waves
            int c  = wave * 4 + cc;
            int lr = c * 8 + srow;             // tile row 0..127
            int gcol = k0 + ((scb ^ (lr & 7)) * 8);
            async_load16(A + (size_t)(row0 + lr) * K + gcol, Ad + c * 512);
            async_load16(W + (size_t)(col0 + lr) * K + gcol, Bd + c * 512);
        }
    };

    stage(0, 0);   // prologue

    for (int t = 0; t < NT; ++t) {
        const int cur = t & 1;
        __syncthreads();   // drains vmcnt -> buf[cur] ready; buf[cur^1] readers done
        if (t + 1 < NT) stage(cur ^ 1, (t + 1) * 64);   // prefetch next tile

        const unsigned short* Ac = As + cur * 8192;
        const unsigned short* Bc = Bs + cur * 8192;

#pragma unroll
        for (int kf = 0; kf < 2; ++kf) {
            const int swz = ((kf * 4 + quad) ^ (l15 & 7)) * 8;
            short8 af[4], bf[4];
#pragma unroll
            for (int mi = 0; mi < 4; mi++)
                af[mi] = *(const short8*)(&Ac[(wm * 64 + mi * 16 + l15) * 64 + swz]);
#pragma unroll
            for (int ni = 0; ni < 4; ni++)
                bf[ni] = *(const short8*)(&Bc[(wn * 64 + ni * 16 + l15) * 64 + swz]);
#pragma unroll
            for (int mi = 0; mi < 4; mi++)
#pragma unroll
                for (int ni = 0; ni < 4; ni++)
                    acc[mi][ni] = __builtin_amdgcn_mfma_f32_16x16x32_bf16(
                        af[mi], bf[ni], acc[mi][ni], 0, 0, 0);
        }
    }

    if (OUT_MODE == 2) {
        // ---- V^T epilogue: LDS transpose staging, coalesced global write ----
        __syncthreads();   // all waves done reading LDS from the last tile
#pragma unroll
        for (int ni = 0; ni < 4; ni++) {
            int c = wn * 64 + ni * 16 + l15;          // local col 0..127
            float bv = bias[col0 + c];
#pragma unroll
            for (int mi = 0; mi < 4; mi++) {
                int r = wm * 64 + mi * 16 + quad * 4; // local row, multiple of 4
                ushort4 pk;
                pk.x = f2bf(acc[mi][ni][0] + bv);
                pk.y = f2bf(acc[mi][ni][1] + bv);
                pk.z = f2bf(acc[mi][ni][2] + bv);
                pk.w = f2bf(acc[mi][ni][3] + bv);
                *(ushort4*)(As + c * 128 + (r ^ ((c & 7) << 3))) = pk;  // XOR swz
            }
        }
        __syncthreads();
        // cooperative coalesced write: 2048 items = 128 cols x 16 row-blocks(16B)
#pragma unroll
        for (int itx = 0; itx < 8; ++itx) {
            int item = itx * 256 + tid;
            int c  = item >> 4;        // 0..127 (16 consecutive lanes share c)
            int rb = item & 15;        // logical 8-elem row block
            uint4v v = *(const uint4v*)(As + c * 128 + ((rb ^ (c & 7)) * 8));
            *(uint4v*)((unsigned short*)Cout + (size_t)(col0 + c) * BN_ + row0 + rb * 8) = v;
        }
        return;
    }

#pragma unroll
    for (int ni = 0; ni < 4; ni++) {
        int col = col0 + wn * 64 + ni * 16 + l15;
        float bv = bias[col];
#pragma unroll
        for (int mi = 0; mi < 4; mi++) {
            int row = row0 + wm * 64 + mi * 16 + quad * 4;
#pragma unroll
            for (int r = 0; r < 4; r++) {
                float v = acc[mi][ni][r] + bv;
                if (OUT_MODE == 3) v *= QSCL;
                if (OUT_MODE == 0)
                    ((float*)Cout)[(size_t)(row + r) * D_ + col] = v;
                else
                    ((unsigned short*)Cout)[(size_t)(row + r) * D_ + col] = f2bf(v);
            }
        }
    }
}

// XCD-aware bijective block swizzle (T1). nwg = 8*32 = 256, nwg%8==0.
__device__ __forceinline__ void xcd_swz(int& bx, int& by) {
    int w = blockIdx.y * 8 + blockIdx.x;      // dispatch-flat (x fastest)
    int s = (w & 7) * 32 + (w >> 3);          // bijective transpose, nwg=256
    bx = s & 7; by = s >> 3;
}

// Kernel 2: fused QKV projection (z selects q/k/v; q pre-scaled, v transposed)
__global__ __launch_bounds__(256) void qkv_gemm(
    const unsigned short* __restrict__ xb,
    const unsigned short* __restrict__ wqb, const unsigned short* __restrict__ wkb,
    const unsigned short* __restrict__ wvb,
    const float* __restrict__ bq, const float* __restrict__ bk, const float* __restrict__ bv,
    unsigned short* __restrict__ q, unsigned short* __restrict__ k, unsigned short* __restrict__ vt)
{
    __shared__ __align__(16) unsigned short As[2 * 128 * 64];   // 32 KB dbuf
    __shared__ __align__(16) unsigned short Bs[2 * 128 * 64];   // 32 KB dbuf
    int bx, by; xcd_swz(bx, by);
    if (blockIdx.z == 0)
        gemm_body<3>(As, Bs, xb, wqb, bq, q,  bx, by);
    else if (blockIdx.z == 1)
        gemm_body<1>(As, Bs, xb, wkb, bk, k,  bx, by);
    else
        gemm_body<2>(As, Bs, xb, wvb, bv, vt, bx, by);
}

// Kernel 4: output projection, fp32 out
__global__ __launch_bounds__(256) void out_gemm(
    const unsigned short* __restrict__ attn, const unsigned short* __restrict__ wob,
    const float* __restrict__ bo, float* __restrict__ out)
{
    __shared__ __align__(16) unsigned short As[2 * 128 * 64];
    __shared__ __align__(16) unsigned short Bs[2 * 128 * 64];
    int bx, by; xcd_swz(bx, by);
    gemm_body<0>(As, Bs, attn, wob, bo, out, bx, by);
}

// ---------------------------------------------------------------------------
// Kernel 3: flash attention — R3-verified single-pass + T5 setprio around
// MFMA clusters (m191: +4-7% when blocks on a CU run at independent phases;
// ours are independent blocks). 128 Q-rows/block, 4 waves, full KV,
// full-rate 32x32x16 PV with in-lane P frags + kq-split b64 V reads.
// ---------------------------------------------------------------------------
__global__ __launch_bounds__(256) void attn_kernel(
    const unsigned short* __restrict__ q, const unsigned short* __restrict__ k,
    const unsigned short* __restrict__ vt, unsigned short* __restrict__ o)
{
    __shared__ __align__(16) unsigned short Ks[2][64 * 64];
    __shared__ __align__(16) unsigned short Vs[2][64 * 64];

    const int tid = threadIdx.x;
    const int lane = tid & 63, wave = tid >> 6;
    const int l31 = lane & 31, kq = lane >> 5;
    const int bh = blockIdx.x;
    const int qt = blockIdx.y;
    const int b = bh >> 4, h = bh & 15;

    const unsigned short* qb = q  + (size_t)b * N_ * D_ + h * DH_;
    const unsigned short* kb = k  + (size_t)b * N_ * D_ + h * DH_;
    const unsigned short* vb = vt + (size_t)h * DH_ * BN_ + (size_t)b * N_;

    const int qrow0 = qt * 128 + wave * 32;

    short8 qf[4];
#pragma unroll
    for (int s = 0; s < 4; s++)
        qf[s] = *(const short8*)(qb + (size_t)(qrow0 + l31) * D_ + s * 16 + kq * 8);

    f32x16 oacc[2] = {};
    float lsum = 0.f;

    const int srow = lane >> 3, scb = lane & 7;

    auto stage = [&](int bi, int kv0) {
#pragma unroll
        for (int cc = 0; cc < 2; ++cc) {
            int c  = wave * 2 + cc;
            int lr = c * 8 + srow;
            int swz8 = (scb ^ (lr & 7)) * 8;
            async_load16(kb + (size_t)(kv0 + lr) * D_ + swz8, (unsigned short*)Ks[bi] + c * 512);
            async_load16(vb + (size_t)lr * BN_ + kv0 + swz8,  (unsigned short*)Vs[bi] + c * 512);
        }
    };

    stage(0, 0);

    const int NIT = N_ / 64;
    for (int it = 0; it < NIT; ++it) {
        const int cur = it & 1;
        __syncthreads();
        if (it + 1 < NIT) stage(cur ^ 1, (it + 1) * 64);

        const unsigned short* Kc = Ks[cur];
        const unsigned short* Vc = Vs[cur];

        f32x16 st[2] = {};
        __builtin_amdgcn_s_setprio(1);
#pragma unroll
        for (int s = 0; s < 4; s++) {
#pragma unroll
            for (int mb = 0; mb < 2; mb++) {
                short8 kfr = *(const short8*)((const char*)Kc +
                    (mb * 32 + l31) * 128 + (((2 * s + kq) ^ (l31 & 7)) * 16));
                st[mb] = __builtin_amdgcn_mfma_f32_32x32x16_bf16(
                    kfr, qf[s], st[mb], 0, 0, 0);
            }
        }
        __builtin_amdgcn_s_setprio(0);

#pragma unroll
        for (int mb = 0; mb < 2; mb++) {
            unsigned int pk[8];
#pragma unroll
            for (int g = 0; g < 4; g++) {
                float p0 = EXP2(st[mb][g * 4 + 0]);
                float p1 = EXP2(st[mb][g * 4 + 1]);
                float p2 = EXP2(st[mb][g * 4 + 2]);
                float p3 = EXP2(st[mb][g * 4 + 3]);
                lsum += (p0 + p1) + (p2 + p3);
                pk[2 * g + 0] = pkbf(p0, p1);
                pk[2 * g + 1] = pkbf(p2, p3);
            }
            __builtin_amdgcn_s_setprio(1);
#pragma unroll
            for (int s = 0; s < 2; s++) {
                uint4v fu;
                fu[0] = pk[4 * s + 0]; fu[1] = pk[4 * s + 1];
                fu[2] = pk[4 * s + 2]; fu[3] = pk[4 * s + 3];
                short8 pf = __builtin_bit_cast(short8, fu);
                const int blkA = 4 * mb + 2 * s;
#pragma unroll
                for (int nb = 0; nb < 2; nb++) {
                    const char* vrow = (const char*)Vc + (nb * 32 + l31) * 128;
                    uint2 vlo = *(const uint2*)(vrow + ((blkA       ^ (l31 & 7)) * 16) + kq * 8);
                    uint2 vhi = *(const uint2*)(vrow + (((blkA + 1) ^ (l31 & 7)) * 16) + kq * 8);
                    uint4v vu; vu[0] = vlo.x; vu[1] = vlo.y; vu[2] = vhi.x; vu[3] = vhi.y;
                    short8 vf = __builtin_bit_cast(short8, vu);
                    oacc[nb] = __builtin_amdgcn_mfma_f32_32x32x16_bf16(
                        pf, vf, oacc[nb], 0, 0, 0);
                }
            }
            __builtin_amdgcn_s_setprio(0);
        }
    }

    lsum += __shfl_xor(lsum, 32);
    __syncthreads();
    float* Lt = (float*)&Ks[0][0] + wave * 32;
    if (kq == 0) Lt[l31] = lsum;
    asm volatile("s_waitcnt lgkmcnt(0)" ::: "memory");

#pragma unroll
    for (int g = 0; g < 4; g++)
#pragma unroll
        for (int rr = 0; rr < 4; rr++) {
            int reg = g * 4 + rr;
            float inv = 1.f / Lt[rr + 8 * g + 4 * kq];
            int row = qrow0 + rr + 8 * g + 4 * kq;
            size_t base = ((size_t)b * N_ + row) * D_ + h * DH_;
#pragma unroll
            for (int nb = 0; nb < 2; nb++)
                o[base + nb * 32 + l31] = f2bf(oacc[nb][reg] * inv);
        }
}

// ---------------------------------------------------------------------------
extern "C" void kernel_launch(void* const* d_in, const int* in_sizes, int n_in,
                              void* d_out, int out_size, void* d_ws, size_t ws_size,
                              hipStream_t stream)
{
    const float* x  = (const float*)d_in[0];
    const float* Wq = (const float*)d_in[1];
    const float* bq = (const float*)d_in[2];
    const float* Wk = (const float*)d_in[3];
    const float* bk = (const float*)d_in[4];
    const float* Wv = (const float*)d_in[5];
    const float* bv = (const float*)d_in[6];
    const float* Wo = (const float*)d_in[7];
    const float* bo = (const float*)d_in[8];
    float* out = (float*)d_out;

    char* ws = (char*)d_ws;
    unsigned short* xb  = (unsigned short*)(ws + 0);         //  8 MB  x bf16
    unsigned short* wqb = (unsigned short*)(ws + 8388608);   //  2 MB
    unsigned short* wkb = (unsigned short*)(ws + 10485760);  //  2 MB
    unsigned short* wvb = (unsigned short*)(ws + 12582912);  //  2 MB
    unsigned short* wob = (unsigned short*)(ws + 14680064);  //  2 MB
    unsigned short* qd  = (unsigned short*)(ws + 16777216);  //  8 MB  Q (pre-scaled)
    unsigned short* kd  = (unsigned short*)(ws + 25165824);  //  8 MB
    unsigned short* vtd = (unsigned short*)(ws + 33554432);  //  8 MB  V^T [D][B*N]
    unsigned short* ad  = (unsigned short*)(ws + 41943040);  //  8 MB  attn out
    // total 48 MB

    cast_kernel<<<8192, 256, 0, stream>>>(x, Wq, Wk, Wv, Wo, xb, wqb, wkb, wvb, wob);
    qkv_gemm<<<dim3(8, 32, 3), 256, 0, stream>>>(xb, wqb, wkb, wvb, bq, bk, bv, qd, kd, vtd);
    attn_kernel<<<dim3(32, 16), 256, 0, stream>>>(qd, kd, vtd, ad);
    out_gemm<<<dim3(8, 32), 256, 0, stream>>>(ad, wob, bo, out);
}

// Round 9
// 196.464 us; speedup vs baseline: 1.0971x; 1.0341x over previous
//
#include <hip/hip_runtime.h>
#include <hip/hip_bf16.h>

// Problem constants
#define B_  2
#define N_  2048
#define D_  1024
#define H_  16
#define DH_ 64
#define BN_ (B_*N_)   // 4096 rows total

typedef __attribute__((ext_vector_type(8))) short short8;    // 8 bf16 (K=16/32 A/B frag)
typedef __attribute__((ext_vector_type(4))) float f32x4;     // 16x16 C/D frag
typedef __attribute__((ext_vector_type(16))) float f32x16;   // 32x32 C/D frag
typedef __attribute__((ext_vector_type(4))) unsigned int uint4v;

typedef __attribute__((address_space(3))) unsigned int lds_u32_t;
typedef const __attribute__((address_space(1))) unsigned int glb_u32_t;

// async global->LDS, 16B per lane; LDS dst = (wave-uniform base) + lane*16
__device__ __forceinline__ void async_load16(const unsigned short* g, unsigned short* l) {
    __builtin_amdgcn_global_load_lds((glb_u32_t*)g, (lds_u32_t*)l, 16, 0, 0);
}

__device__ __forceinline__ unsigned short f2bf(float f) {
    __hip_bfloat16 h = __float2bfloat16(f);
    return *reinterpret_cast<unsigned short*>(&h);
}

// pack bf16(a) low16 | bf16(b) high16; round-half-up + one v_perm_b32
__device__ __forceinline__ unsigned int pkbf(float a, float b) {
    unsigned int ua = __float_as_uint(a) + 0x8000u;
    unsigned int ub = __float_as_uint(b) + 0x8000u;
    return __builtin_amdgcn_perm(ub, ua, 0x07060302);
}

#if __has_builtin(__builtin_amdgcn_exp2f)
#define EXP2(x) __builtin_amdgcn_exp2f(x)
#else
#define EXP2(x) exp2f(x)
#endif

// softmax scale folded into Q projection: 1/sqrt(DH) * log2(e)
#define QSCL 0.1803368801111204f

// ---------------------------------------------------------------------------
// Kernel 1: cast fp32 -> bf16 for x, Wq, Wk, Wv, Wo (one fused launch)
// ---------------------------------------------------------------------------
__global__ __launch_bounds__(256) void cast_kernel(
    const float* __restrict__ x,  const float* __restrict__ wq,
    const float* __restrict__ wk, const float* __restrict__ wv,
    const float* __restrict__ wo,
    unsigned short* __restrict__ xb,  unsigned short* __restrict__ wqb,
    unsigned short* __restrict__ wkb, unsigned short* __restrict__ wvb,
    unsigned short* __restrict__ wob)
{
    const size_t NX = (size_t)BN_ * D_;   // 4194304
    const size_t NW = (size_t)D_ * D_;    // 1048576 (pow2)
    size_t i = ((size_t)blockIdx.x * 256 + threadIdx.x) * 4;
    const float* src; unsigned short* dst; size_t off;
    if (i < NX) { src = x; dst = xb; off = i; }
    else {
        size_t j = (i - NX) >> 20;          // which W
        off = (i - NX) & (NW - 1);
        src = (j == 0) ? wq : (j == 1) ? wk : (j == 2) ? wv : wo;
        dst = (j == 0) ? wqb : (j == 1) ? wkb : (j == 2) ? wvb : wob;
    }
    float4 v = *(const float4*)(src + off);
    ushort4 o;
    o.x = f2bf(v.x); o.y = f2bf(v.y); o.z = f2bf(v.z); o.w = f2bf(v.w);
    *(ushort4*)(dst + off) = o;
}

// ---------------------------------------------------------------------------
// GEMM body, R9 shape: 64x128 tile (BM=64), 4 waves x (64x32 acc[4][2]),
// single-buffered 24 KB LDS.
// WHY: per-SIMD cost model (calibrated on attn: 32x32x16 MFMA ~39 cyc/SIMD,
// MfmaUtil 26% pred vs 22-25% meas) puts qkv+out MFMA floor at ~17 us, but
// subtraction says they cost ~139 us at 1-3 waves/SIMD — pure latency
// exposure (m102's 90-320 TF at small N, same structure). R8's dbuf was
// ~null (catalog m99/m100) and halved residency. So: revert dbuf, shrink
// BM 128->64 => qkv 1536 blocks (6/CU LDS-cap, ~5 waves/SIMD VGPR-cap),
// out 512 blocks (2/CU vs 1). MFMA work invariant; latency hiding 2.5-5x.
// ---------------------------------------------------------------------------
template<int OUT_MODE>
__device__ __forceinline__ void gemm_body(
    unsigned short* __restrict__ As, unsigned short* __restrict__ Bs,
    const unsigned short* __restrict__ A, const unsigned short* __restrict__ W,
    const float* __restrict__ bias, void* __restrict__ Cout, int bx, int by)
{
    constexpr int K = D_;
    const int tid  = threadIdx.x;
    const int lane = tid & 63;
    const int wave = tid >> 6;
    const int l15 = lane & 15, quad = lane >> 4;

    f32x4 acc[4][2] = {};
    const int row0 = by * 64, col0 = bx * 128;

    const int srow = lane >> 3;   // row within 1KB chunk (8 rows x 128B)
    const int scb  = lane & 7;    // 16B block within row

    for (int k0 = 0; k0 < K; k0 += 64) {
        __syncthreads();
        // A tile: 64 rows = 8 chunks; B tile: 128 rows = 16 chunks
#pragma unroll
        for (int cc = 0; cc < 2; ++cc) {
            int c  = wave * 2 + cc;            // 0..7
            int lr = c * 8 + srow;             // A row 0..63
            int gcol = k0 + ((scb ^ (lr & 7)) * 8);
            async_load16(A + (size_t)(row0 + lr) * K + gcol, As + c * 512);
        }
#pragma unroll
        for (int cc = 0; cc < 4; ++cc) {
            int c  = wave * 4 + cc;            // 0..15
            int lr = c * 8 + srow;             // B row (out col) 0..127
            int gcol = k0 + ((scb ^ (lr & 7)) * 8);
            async_load16(W + (size_t)(col0 + lr) * K + gcol, Bs + c * 512);
        }
        __syncthreads();

#pragma unroll
        for (int kf = 0; kf < 2; ++kf) {
            const int swz = ((kf * 4 + quad) ^ (l15 & 7)) * 8;
            short8 af[4], bf[2];
#pragma unroll
            for (int mi = 0; mi < 4; mi++)
                af[mi] = *(const short8*)(&As[(mi * 16 + l15) * 64 + swz]);
#pragma unroll
            for (int ni = 0; ni < 2; ni++)
                bf[ni] = *(const short8*)(&Bs[(wave * 32 + ni * 16 + l15) * 64 + swz]);
#pragma unroll
            for (int mi = 0; mi < 4; mi++)
#pragma unroll
                for (int ni = 0; ni < 2; ni++)
                    acc[mi][ni] = __builtin_amdgcn_mfma_f32_16x16x32_bf16(
                        af[mi], bf[ni], acc[mi][ni], 0, 0, 0);
        }
    }

    if (OUT_MODE == 2) {
        // ---- V^T epilogue: stage 128c x 64r tile in Bs (8192 shorts, exact),
        //      XOR-swizzled, then coalesced 16B runs along BN ----
        __syncthreads();   // all waves done reading LDS from the last tile
#pragma unroll
        for (int ni = 0; ni < 2; ni++) {
            int c = wave * 32 + ni * 16 + l15;        // local col 0..127
            float bv = bias[col0 + c];
#pragma unroll
            for (int mi = 0; mi < 4; mi++) {
                int r = mi * 16 + quad * 4;           // local row, multiple of 4
                ushort4 pk;
                pk.x = f2bf(acc[mi][ni][0] + bv);
                pk.y = f2bf(acc[mi][ni][1] + bv);
                pk.z = f2bf(acc[mi][ni][2] + bv);
                pk.w = f2bf(acc[mi][ni][3] + bv);
                *(ushort4*)(Bs + c * 64 + (r ^ ((c & 7) << 3))) = pk;  // XOR swz
            }
        }
        __syncthreads();
        // 1024 items = 128 cols x 8 row-blocks(16B); 8 consecutive lanes share c
#pragma unroll
        for (int itx = 0; itx < 4; ++itx) {
            int item = itx * 256 + tid;
            int c  = item >> 3;        // 0..127
            int rb = item & 7;         // logical 8-elem row block
            uint4v v = *(const uint4v*)(Bs + c * 64 + ((rb ^ (c & 7)) * 8));
            *(uint4v*)((unsigned short*)Cout + (size_t)(col0 + c) * BN_ + row0 + rb * 8) = v;
        }
        return;
    }

#pragma unroll
    for (int ni = 0; ni < 2; ni++) {
        int col = col0 + wave * 32 + ni * 16 + l15;
        float bv = bias[col];
#pragma unroll
        for (int mi = 0; mi < 4; mi++) {
            int row = row0 + mi * 16 + quad * 4;
#pragma unroll
            for (int r = 0; r < 4; r++) {
                float v = acc[mi][ni][r] + bv;
                if (OUT_MODE == 3) v *= QSCL;
                if (OUT_MODE == 0)
                    ((float*)Cout)[(size_t)(row + r) * D_ + col] = v;
                else
                    ((unsigned short*)Cout)[(size_t)(row + r) * D_ + col] = f2bf(v);
            }
        }
    }
}

// XCD-aware bijective block swizzle (T1), nwg = 8x64 = 512 per z-slice.
// XCD k gets by-panels [8k..8k+7] x all bx: ~1 MB A + 2 MB W < 4 MB L2.
__device__ __forceinline__ void xcd_swz(int& bx, int& by) {
    int w = blockIdx.y * 8 + blockIdx.x;      // dispatch-flat (x fastest)
    int s = (w & 7) * 64 + (w >> 3);          // bijective, nwg=512
    bx = s & 7; by = s >> 3;
}

// Kernel 2: fused QKV projection (z selects q/k/v; q pre-scaled, v transposed)
__global__ __launch_bounds__(256, 5) void qkv_gemm(
    const unsigned short* __restrict__ xb,
    const unsigned short* __restrict__ wqb, const unsigned short* __restrict__ wkb,
    const unsigned short* __restrict__ wvb,
    const float* __restrict__ bq, const float* __restrict__ bk, const float* __restrict__ bv,
    unsigned short* __restrict__ q, unsigned short* __restrict__ k, unsigned short* __restrict__ vt)
{
    __shared__ __align__(16) unsigned short As[64 * 64];    //  8 KB
    __shared__ __align__(16) unsigned short Bs[128 * 64];   // 16 KB
    int bx, by; xcd_swz(bx, by);
    if (blockIdx.z == 0)
        gemm_body<3>(As, Bs, xb, wqb, bq, q,  bx, by);
    else if (blockIdx.z == 1)
        gemm_body<1>(As, Bs, xb, wkb, bk, k,  bx, by);
    else
        gemm_body<2>(As, Bs, xb, wvb, bv, vt, bx, by);
}

// Kernel 4: output projection, fp32 out
__global__ __launch_bounds__(256, 5) void out_gemm(
    const unsigned short* __restrict__ attn, const unsigned short* __restrict__ wob,
    const float* __restrict__ bo, float* __restrict__ out)
{
    __shared__ __align__(16) unsigned short As[64 * 64];
    __shared__ __align__(16) unsigned short Bs[128 * 64];
    int bx, by; xcd_swz(bx, by);
    gemm_body<0>(As, Bs, attn, wob, bo, out, bx, by);
}

// ---------------------------------------------------------------------------
// Kernel 3: flash attention — R3-verified single-pass + T5 setprio (R8:
// attn 65.5 -> ~63.8, kept). 128 Q-rows/block, 4 waves, full KV,
// full-rate 32x32x16 PV with in-lane P frags + kq-split b64 V reads.
// ---------------------------------------------------------------------------
__global__ __launch_bounds__(256) void attn_kernel(
    const unsigned short* __restrict__ q, const unsigned short* __restrict__ k,
    const unsigned short* __restrict__ vt, unsigned short* __restrict__ o)
{
    __shared__ __align__(16) unsigned short Ks[2][64 * 64];
    __shared__ __align__(16) unsigned short Vs[2][64 * 64];

    const int tid = threadIdx.x;
    const int lane = tid & 63, wave = tid >> 6;
    const int l31 = lane & 31, kq = lane >> 5;
    const int bh = blockIdx.x;
    const int qt = blockIdx.y;
    const int b = bh >> 4, h = bh & 15;

    const unsigned short* qb = q  + (size_t)b * N_ * D_ + h * DH_;
    const unsigned short* kb = k  + (size_t)b * N_ * D_ + h * DH_;
    const unsigned short* vb = vt + (size_t)h * DH_ * BN_ + (size_t)b * N_;

    const int qrow0 = qt * 128 + wave * 32;

    short8 qf[4];
#pragma unroll
    for (int s = 0; s < 4; s++)
        qf[s] = *(const short8*)(qb + (size_t)(qrow0 + l31) * D_ + s * 16 + kq * 8);

    f32x16 oacc[2] = {};
    float lsum = 0.f;

    const int srow = lane >> 3, scb = lane & 7;

    auto stage = [&](int bi, int kv0) {
#pragma unroll
        for (int cc = 0; cc < 2; ++cc) {
            int c  = wave * 2 + cc;
            int lr = c * 8 + srow;
            int swz8 = (scb ^ (lr & 7)) * 8;
            async_load16(kb + (size_t)(kv0 + lr) * D_ + swz8, (unsigned short*)Ks[bi] + c * 512);
            async_load16(vb + (size_t)lr * BN_ + kv0 + swz8,  (unsigned short*)Vs[bi] + c * 512);
        }
    };

    stage(0, 0);

    const int NIT = N_ / 64;
    for (int it = 0; it < NIT; ++it) {
        const int cur = it & 1;
        __syncthreads();
        if (it + 1 < NIT) stage(cur ^ 1, (it + 1) * 64);

        const unsigned short* Kc = Ks[cur];
        const unsigned short* Vc = Vs[cur];

        f32x16 st[2] = {};
        __builtin_amdgcn_s_setprio(1);
#pragma unroll
        for (int s = 0; s < 4; s++) {
#pragma unroll
            for (int mb = 0; mb < 2; mb++) {
                short8 kfr = *(const short8*)((const char*)Kc +
                    (mb * 32 + l31) * 128 + (((2 * s + kq) ^ (l31 & 7)) * 16));
                st[mb] = __builtin_amdgcn_mfma_f32_32x32x16_bf16(
                    kfr, qf[s], st[mb], 0, 0, 0);
            }
        }
        __builtin_amdgcn_s_setprio(0);

#pragma unroll
        for (int mb = 0; mb < 2; mb++) {
            unsigned int pk[8];
#pragma unroll
            for (int g = 0; g < 4; g++) {
                float p0 = EXP2(st[mb][g * 4 + 0]);
                float p1 = EXP2(st[mb][g * 4 + 1]);
                float p2 = EXP2(st[mb][g * 4 + 2]);
                float p3 = EXP2(st[mb][g * 4 + 3]);
                lsum += (p0 + p1) + (p2 + p3);
                pk[2 * g + 0] = pkbf(p0, p1);
                pk[2 * g + 1] = pkbf(p2, p3);
            }
            __builtin_amdgcn_s_setprio(1);
#pragma unroll
            for (int s = 0; s < 2; s++) {
                uint4v fu;
                fu[0] = pk[4 * s + 0]; fu[1] = pk[4 * s + 1];
                fu[2] = pk[4 * s + 2]; fu[3] = pk[4 * s + 3];
                short8 pf = __builtin_bit_cast(short8, fu);
                const int blkA = 4 * mb + 2 * s;
#pragma unroll
                for (int nb = 0; nb < 2; nb++) {
                    const char* vrow = (const char*)Vc + (nb * 32 + l31) * 128;
                    uint2 vlo = *(const uint2*)(vrow + ((blkA       ^ (l31 & 7)) * 16) + kq * 8);
                    uint2 vhi = *(const uint2*)(vrow + (((blkA + 1) ^ (l31 & 7)) * 16) + kq * 8);
                    uint4v vu; vu[0] = vlo.x; vu[1] = vlo.y; vu[2] = vhi.x; vu[3] = vhi.y;
                    short8 vf = __builtin_bit_cast(short8, vu);
                    oacc[nb] = __builtin_amdgcn_mfma_f32_32x32x16_bf16(
                        pf, vf, oacc[nb], 0, 0, 0);
                }
            }
            __builtin_amdgcn_s_setprio(0);
        }
    }

    lsum += __shfl_xor(lsum, 32);
    __syncthreads();
    float* Lt = (float*)&Ks[0][0] + wave * 32;
    if (kq == 0) Lt[l31] = lsum;
    asm volatile("s_waitcnt lgkmcnt(0)" ::: "memory");

#pragma unroll
    for (int g = 0; g < 4; g++)
#pragma unroll
        for (int rr = 0; rr < 4; rr++) {
            int reg = g * 4 + rr;
            float inv = 1.f / Lt[rr + 8 * g + 4 * kq];
            int row = qrow0 + rr + 8 * g + 4 * kq;
            size_t base = ((size_t)b * N_ + row) * D_ + h * DH_;
#pragma unroll
            for (int nb = 0; nb < 2; nb++)
                o[base + nb * 32 + l31] = f2bf(oacc[nb][reg] * inv);
        }
}

// ---------------------------------------------------------------------------
extern "C" void kernel_launch(void* const* d_in, const int* in_sizes, int n_in,
                              void* d_out, int out_size, void* d_ws, size_t ws_size,
                              hipStream_t stream)
{
    const float* x  = (const float*)d_in[0];
    const float* Wq = (const float*)d_in[1];
    const float* bq = (const float*)d_in[2];
    const float* Wk = (const float*)d_in[3];
    const float* bk = (const float*)d_in[4];
    const float* Wv = (const float*)d_in[5];
    const float* bv = (const float*)d_in[6];
    const float* Wo = (const float*)d_in[7];
    const float* bo = (const float*)d_in[8];
    float* out = (float*)d_out;

    char* ws = (char*)d_ws;
    unsigned short* xb  = (unsigned short*)(ws + 0);         //  8 MB  x bf16
    unsigned short* wqb = (unsigned short*)(ws + 8388608);   //  2 MB
    unsigned short* wkb = (unsigned short*)(ws + 10485760);  //  2 MB
    unsigned short* wvb = (unsigned short*)(ws + 12582912);  //  2 MB
    unsigned short* wob = (unsigned short*)(ws + 14680064);  //  2 MB
    unsigned short* qd  = (unsigned short*)(ws + 16777216);  //  8 MB  Q (pre-scaled)
    unsigned short* kd  = (unsigned short*)(ws + 25165824);  //  8 MB
    unsigned short* vtd = (unsigned short*)(ws + 33554432);  //  8 MB  V^T [D][B*N]
    unsigned short* ad  = (unsigned short*)(ws + 41943040);  //  8 MB  attn out
    // total 48 MB

    cast_kernel<<<8192, 256, 0, stream>>>(x, Wq, Wk, Wv, Wo, xb, wqb, wkb, wvb, wob);
    qkv_gemm<<<dim3(8, 64, 3), 256, 0, stream>>>(xb, wqb, wkb, wvb, bq, bk, bv, qd, kd, vtd);
    attn_kernel<<<dim3(32, 16), 256, 0, stream>>>(qd, kd, vtd, ad);
    out_gemm<<<dim3(8, 64), 256, 0, stream>>>(ad, wob, bo, out);
}